// Round 3
// baseline (289.445 us; speedup 1.0000x reference)
//
#include <hip/hip_runtime.h>
#include <math.h>

#define N_NODES 30000
#define N_EDGES 480000
#define DIM     128
#define EPSV    1e-5f

// ---------------- init ----------------
__global__ void zero_kernel(int* __restrict__ counts, float* __restrict__ redbuf) {
    int i = blockIdx.x * blockDim.x + threadIdx.x;
    if (i < N_NODES) counts[i] = 0;
    if (i < 2 * DIM) redbuf[i] = 0.0f;
}

// ---------------- CSR build ----------------
__global__ void count_kernel(const int* __restrict__ dst, int* __restrict__ counts) {
    int i = blockIdx.x * blockDim.x + threadIdx.x;
    if (i < N_EDGES) atomicAdd(&counts[dst[i]], 1);
}

// single-block exclusive scan over counts -> offsets (and cursor copy)
__global__ __launch_bounds__(1024) void scan_kernel(const int* __restrict__ counts,
                                                    int* __restrict__ offsets,
                                                    int* __restrict__ cursor) {
    __shared__ int wavebuf[16];
    __shared__ int tilebase;
    __shared__ int tiletotal;
    int tid = threadIdx.x;
    int lane = tid & 63, wv = tid >> 6;
    if (tid == 0) tilebase = 0;
    __syncthreads();
    for (int base = 0; base < N_NODES; base += 1024) {
        int i = base + tid;
        int v = (i < N_NODES) ? counts[i] : 0;
        int sc = v;
        #pragma unroll
        for (int off = 1; off < 64; off <<= 1) {
            int t = __shfl_up(sc, off);
            if (lane >= off) sc += t;
        }
        if (lane == 63) wavebuf[wv] = sc;
        __syncthreads();
        if (wv == 0) {
            int wval = (lane < 16) ? wavebuf[lane] : 0;
            int wsc = wval;
            #pragma unroll
            for (int off = 1; off < 16; off <<= 1) {
                int t = __shfl_up(wsc, off);
                if (lane >= off) wsc += t;
            }
            if (lane < 16) wavebuf[lane] = wsc - wval;   // exclusive wave offsets
            if (lane == 15) tiletotal = wsc;
        }
        __syncthreads();
        int excl = (sc - v) + wavebuf[wv] + tilebase;
        if (i < N_NODES) { offsets[i] = excl; cursor[i] = excl; }
        __syncthreads();
        if (tid == 0) tilebase += tiletotal;
        __syncthreads();
    }
    if (tid == 0) offsets[N_NODES] = tilebase;
}

__global__ void fill_kernel(const int* __restrict__ src, const int* __restrict__ dst,
                            int* __restrict__ cursor, int* __restrict__ edge_src) {
    int i = blockIdx.x * blockDim.x + threadIdx.x;
    if (i < N_EDGES) {
        int p = atomicAdd(&cursor[dst[i]], 1);
        edge_src[p] = src[i];
    }
}

// ---------------- z = h @ W^T (fp32, VALU) ----------------
// block = 256 threads computes a 16x128 tile of z. W (128x128 f32) in LDS,
// h tile (16x128 f32) in LDS. Thread (c = t&127, rbase = (t>>7)*8) computes
// 8 rows of column c.
__global__ __launch_bounds__(256) void gemm_kernel(const float* __restrict__ h,
                                                   const float* __restrict__ W,
                                                   float* __restrict__ z) {
    __shared__ float wsm[128][132];   // 67,584 B (pad 132 breaks pow2 stride)
    __shared__ float hs[16][132];     //  8,448 B
    int t = threadIdx.x;
    int row0 = blockIdx.x * 16;       // grid = 1875 exact
    for (int i = t; i < 4096; i += 256) {     // stage W: 4096 x float4
        int c = i >> 5;
        int k0 = (i & 31) * 4;
        float4 v = *reinterpret_cast<const float4*>(W + c * DIM + k0);
        *reinterpret_cast<float4*>(&wsm[c][k0]) = v;
    }
    for (int i = t; i < 512; i += 256) {      // stage h tile: 512 x float4
        int r = i >> 5;
        int k0 = (i & 31) * 4;
        float4 v = *reinterpret_cast<const float4*>(h + (size_t)(row0 + r) * DIM + k0);
        *reinterpret_cast<float4*>(&hs[r][k0]) = v;
    }
    __syncthreads();
    int c = t & 127;
    int rbase = (t >> 7) * 8;
    float acc[8] = {0.f, 0.f, 0.f, 0.f, 0.f, 0.f, 0.f, 0.f};
    for (int k4 = 0; k4 < 32; ++k4) {
        int k = k4 * 4;
        float4 wv4 = *reinterpret_cast<const float4*>(&wsm[c][k]);
        #pragma unroll
        for (int r = 0; r < 8; ++r) {
            float4 hv = *reinterpret_cast<const float4*>(&hs[rbase + r][k]);
            acc[r] += hv.x * wv4.x + hv.y * wv4.y + hv.z * wv4.z + hv.w * wv4.w;
        }
    }
    #pragma unroll
    for (int r = 0; r < 8; ++r)
        z[(size_t)(row0 + rbase + r) * DIM + c] = acc[r];
}

// ---------------- per-node online softmax + weighted aggregate ----------------
// one wave per dst node; lane handles channels (2*lane, 2*lane+1) as float2.
__global__ __launch_bounds__(256) void node_kernel(const float* __restrict__ z,
                                                   const int* __restrict__ offsets,
                                                   const int* __restrict__ edge_src,
                                                   const float* __restrict__ snorm,
                                                   float* __restrict__ hout) {
    int tid = threadIdx.x;
    int lane = tid & 63;
    int node = blockIdx.x * 4 + (tid >> 6);   // grid = 7500 exact
    const float2* zp = reinterpret_cast<const float2*>(z);
    float2 zd = zp[(size_t)node * 64 + lane];
    int start = offsets[node], end = offsets[node + 1];
    float m0 = -INFINITY, m1 = -INFINITY;
    float s0 = 0.f, s1 = 0.f, w0 = 0.f, w1 = 0.f;
    for (int base = start; base < end; base += 64) {
        int cnt = min(64, end - base);
        int es = (base + lane < end) ? edge_src[base + lane] : 0;
        for (int j = 0; j < cnt; ++j) {
            int sn = __shfl(es, j);
            float2 zs = zp[(size_t)sn * 64 + lane];
            float e0 = zs.x * zd.x, e1 = zs.y * zd.y;
            float nm0 = fmaxf(m0, e0), nm1 = fmaxf(m1, e1);
            float sc0 = __expf(m0 - nm0), sc1 = __expf(m1 - nm1);
            float p0 = __expf(e0 - nm0), p1 = __expf(e1 - nm1);
            s0 = s0 * sc0 + p0;          s1 = s1 * sc1 + p1;
            w0 = w0 * sc0 + p0 * zs.x;   w1 = w1 * sc1 + p1 * zs.y;
            m0 = nm0;                    m1 = nm1;
        }
    }
    float snv = snorm[node];
    float2 o;
    o.x = (s0 > 0.f) ? (w0 / s0) * snv : 0.f;
    o.y = (s1 > 0.f) ? (w1 / s1) * snv : 0.f;
    reinterpret_cast<float2*>(hout)[(size_t)node * 64 + lane] = o;
}

// ---------------- batch-norm statistics ----------------
__global__ __launch_bounds__(256) void reduce_kernel(const float* __restrict__ hout,
                                                     float* __restrict__ redbuf) {
    __shared__ float lsum[256], lsq[256];
    int tid = threadIdx.x;
    int c = tid & 127;
    int half = tid >> 7;
    int rbeg = blockIdx.x * 300;              // grid = 100 exact
    float s = 0.f, q = 0.f;
    for (int r = rbeg + half; r < rbeg + 300; r += 2) {
        float v = hout[(size_t)r * DIM + c];
        s += v; q += v * v;
    }
    lsum[tid] = s; lsq[tid] = q;
    __syncthreads();
    if (tid < 128) {
        s = lsum[tid] + lsum[tid + 128];
        q = lsq[tid] + lsq[tid + 128];
        atomicAdd(&redbuf[c], s);
        atomicAdd(&redbuf[DIM + c], q);
    }
}

__global__ void finalize_kernel(const float* __restrict__ redbuf,
                                const float* __restrict__ gamma,
                                const float* __restrict__ beta,
                                float* __restrict__ params) {
    int c = threadIdx.x;   // 128 threads
    float mu = redbuf[c] * (1.0f / N_NODES);
    float var = redbuf[DIM + c] * (1.0f / N_NODES) - mu * mu;
    float scale = gamma[c] * rsqrtf(var + EPSV);
    params[c] = scale;
    params[DIM + c] = beta[c] - mu * scale;
}

// ---------------- fused BN + ELU + fp32 store ----------------
__global__ __launch_bounds__(256) void elu_kernel(const float* __restrict__ hout,
                                                  const float* __restrict__ params,
                                                  float* __restrict__ out) {
    int idx = (blockIdx.x * 256 + threadIdx.x) * 4;   // grid = 3750 exact
    int c = idx & 127;
    float4 v = reinterpret_cast<const float4*>(hout)[idx >> 2];
    float4 o;
    {
        float y = v.x * params[c + 0] + params[DIM + c + 0];
        o.x = (y > 0.f) ? y : expm1f(y);
        y = v.y * params[c + 1] + params[DIM + c + 1];
        o.y = (y > 0.f) ? y : expm1f(y);
        y = v.z * params[c + 2] + params[DIM + c + 2];
        o.z = (y > 0.f) ? y : expm1f(y);
        y = v.w * params[c + 3] + params[DIM + c + 3];
        o.w = (y > 0.f) ? y : expm1f(y);
    }
    reinterpret_cast<float4*>(out)[idx >> 2] = o;
}

extern "C" void kernel_launch(void* const* d_in, const int* in_sizes, int n_in,
                              void* d_out, int out_size, void* d_ws, size_t ws_size,
                              hipStream_t stream) {
    const float* h     = (const float*)d_in[0];
    const float* snorm = (const float*)d_in[1];
    const float* W     = (const float*)d_in[2];
    const float* gamma = (const float*)d_in[3];
    const float* beta  = (const float*)d_in[4];
    const int*   src   = (const int*)d_in[5];
    const int*   dst   = (const int*)d_in[6];
    float*       out   = (float*)d_out;

    char* ws = (char*)d_ws;
    float* z        = (float*)(ws + 0);          // 15,360,000 B
    float* hout     = (float*)(ws + 15360000);   // 15,360,000 B
    int*   counts   = (int*)  (ws + 30720000);   //    120,000 B
    int*   offsets  = (int*)  (ws + 30840000);   //    120,004 B
    int*   cursor   = (int*)  (ws + 30960016);   //    120,000 B
    int*   edge_src = (int*)  (ws + 31080016);   //  1,920,000 B
    float* redbuf   = (float*)(ws + 33000016);   //      1,024 B
    float* params   = (float*)(ws + 33001040);   //      1,024 B

    zero_kernel<<<118, 256, 0, stream>>>(counts, redbuf);
    count_kernel<<<(N_EDGES + 255) / 256, 256, 0, stream>>>(dst, counts);
    scan_kernel<<<1, 1024, 0, stream>>>(counts, offsets, cursor);
    fill_kernel<<<(N_EDGES + 255) / 256, 256, 0, stream>>>(src, dst, cursor, edge_src);
    gemm_kernel<<<1875, 256, 0, stream>>>(h, W, z);
    node_kernel<<<N_NODES / 4, 256, 0, stream>>>(z, offsets, edge_src, snorm, hout);
    reduce_kernel<<<100, 256, 0, stream>>>(hout, redbuf);
    finalize_kernel<<<1, 128, 0, stream>>>(redbuf, gamma, beta, params);
    elu_kernel<<<(N_NODES * DIM) / 1024, 256, 0, stream>>>(hout, params, out);
}

// Round 4
// 264.968 us; speedup vs baseline: 1.0924x; 1.0924x over previous
//
#include <hip/hip_runtime.h>
#include <math.h>

#define N_NODES 30000
#define N_EDGES 480000
#define DIM     128
#define EPSV    1e-5f

// ---------------- init ----------------
__global__ void zero_kernel(int* __restrict__ counts, float* __restrict__ redbuf,
                            int* __restrict__ zmax) {
    int i = blockIdx.x * blockDim.x + threadIdx.x;
    if (i < N_NODES) counts[i] = 0;
    if (i < 2 * DIM) redbuf[i] = 0.0f;
    if (i == 0) zmax[0] = 0;
}

// ---------------- CSR build ----------------
__global__ void count_kernel(const int* __restrict__ dst, int* __restrict__ counts) {
    int i = blockIdx.x * blockDim.x + threadIdx.x;
    if (i < N_EDGES) atomicAdd(&counts[dst[i]], 1);
}

__global__ __launch_bounds__(1024) void scan_kernel(const int* __restrict__ counts,
                                                    int* __restrict__ offsets,
                                                    int* __restrict__ cursor) {
    __shared__ int wavebuf[16];
    __shared__ int tilebase;
    __shared__ int tiletotal;
    int tid = threadIdx.x;
    int lane = tid & 63, wv = tid >> 6;
    if (tid == 0) tilebase = 0;
    __syncthreads();
    for (int base = 0; base < N_NODES; base += 1024) {
        int i = base + tid;
        int v = (i < N_NODES) ? counts[i] : 0;
        int sc = v;
        #pragma unroll
        for (int off = 1; off < 64; off <<= 1) {
            int t = __shfl_up(sc, off);
            if (lane >= off) sc += t;
        }
        if (lane == 63) wavebuf[wv] = sc;
        __syncthreads();
        if (wv == 0) {
            int wval = (lane < 16) ? wavebuf[lane] : 0;
            int wsc = wval;
            #pragma unroll
            for (int off = 1; off < 16; off <<= 1) {
                int t = __shfl_up(wsc, off);
                if (lane >= off) wsc += t;
            }
            if (lane < 16) wavebuf[lane] = wsc - wval;
            if (lane == 15) tiletotal = wsc;
        }
        __syncthreads();
        int excl = (sc - v) + wavebuf[wv] + tilebase;
        if (i < N_NODES) { offsets[i] = excl; cursor[i] = excl; }
        __syncthreads();
        if (tid == 0) tilebase += tiletotal;
        __syncthreads();
    }
    if (tid == 0) offsets[N_NODES] = tilebase;
}

__global__ void fill_kernel(const int* __restrict__ src, const int* __restrict__ dst,
                            int* __restrict__ cursor, int* __restrict__ edge_src) {
    int i = blockIdx.x * blockDim.x + threadIdx.x;
    if (i < N_EDGES) {
        int p = atomicAdd(&cursor[dst[i]], 1);
        edge_src[p] = src[i];
    }
}

// ---------------- z = h @ W^T (fp32 VALU, 64x128 block tile) ----------------
// 256 threads: thread (tx=t&31, ty=t>>5) computes rows ty*8..+7 x cols tx*4..+3.
// Per k4: 12 ds_read_b128 (~120 cyc) vs 128 FMA (256 cyc) -> VALU-bound.
// Epilogue also writes fp16 copy z2 and global max|z| (for the softmax offset).
__global__ __launch_bounds__(256) void gemm_kernel(const float* __restrict__ h,
                                                   const float* __restrict__ W,
                                                   float* __restrict__ z,
                                                   unsigned short* __restrict__ z2,
                                                   int* __restrict__ zmax) {
    __shared__ float wsm[128][68];    // 34,816 B (pad 68 -> 2x16-way, under FMA budget)
    __shared__ float hs[64][128];     // 32,768 B ; total 67,584 -> 2 blocks/CU
    int t = threadIdx.x;
    int row0 = blockIdx.x * 64;       // grid = 469 (tail guarded)
    int tx = t & 31, ty = t >> 5;
    for (int i = t; i < 2048; i += 256) {        // stage h tile
        int r = i >> 5, k4 = i & 31;
        int rr = row0 + r; if (rr > N_NODES - 1) rr = N_NODES - 1;
        *reinterpret_cast<float4*>(&hs[r][k4 * 4]) =
            *reinterpret_cast<const float4*>(h + (size_t)rr * DIM + k4 * 4);
    }
    float acc[8][4];
    #pragma unroll
    for (int r = 0; r < 8; ++r)
        #pragma unroll
        for (int c = 0; c < 4; ++c) acc[r][c] = 0.f;

    for (int half = 0; half < 2; ++half) {
        __syncthreads();                          // hs ready / prev wsm reads done
        for (int i = t; i < 2048; i += 256) {     // stage W k-half: 128c x 64k
            int c = i >> 4, k4 = i & 15;
            *reinterpret_cast<float4*>(&wsm[c][k4 * 4]) =
                *reinterpret_cast<const float4*>(W + (size_t)c * DIM + half * 64 + k4 * 4);
        }
        __syncthreads();
        #pragma unroll 4
        for (int k4 = 0; k4 < 16; ++k4) {
            float4 wv0 = *reinterpret_cast<const float4*>(&wsm[tx * 4 + 0][k4 * 4]);
            float4 wv1 = *reinterpret_cast<const float4*>(&wsm[tx * 4 + 1][k4 * 4]);
            float4 wv2 = *reinterpret_cast<const float4*>(&wsm[tx * 4 + 2][k4 * 4]);
            float4 wv3 = *reinterpret_cast<const float4*>(&wsm[tx * 4 + 3][k4 * 4]);
            #pragma unroll
            for (int r = 0; r < 8; ++r) {
                float4 hv = *reinterpret_cast<const float4*>(&hs[ty * 8 + r][half * 64 + k4 * 4]);
                acc[r][0] += hv.x * wv0.x + hv.y * wv0.y + hv.z * wv0.z + hv.w * wv0.w;
                acc[r][1] += hv.x * wv1.x + hv.y * wv1.y + hv.z * wv1.z + hv.w * wv1.w;
                acc[r][2] += hv.x * wv2.x + hv.y * wv2.y + hv.z * wv2.z + hv.w * wv2.w;
                acc[r][3] += hv.x * wv3.x + hv.y * wv3.y + hv.z * wv3.z + hv.w * wv3.w;
            }
        }
    }
    float amax = 0.f;
    #pragma unroll
    for (int r = 0; r < 8; ++r) {
        int row = row0 + ty * 8 + r;
        float a0 = acc[r][0], a1 = acc[r][1], a2 = acc[r][2], a3 = acc[r][3];
        amax = fmaxf(amax, fmaxf(fmaxf(fabsf(a0), fabsf(a1)), fmaxf(fabsf(a2), fabsf(a3))));
        if (row < N_NODES) {
            float4 v = {a0, a1, a2, a3};
            *reinterpret_cast<float4*>(z + (size_t)row * DIM + tx * 4) = v;
            union { ushort4 u; _Float16 f[4]; } pk;
            pk.f[0] = (_Float16)a0; pk.f[1] = (_Float16)a1;
            pk.f[2] = (_Float16)a2; pk.f[3] = (_Float16)a3;
            *reinterpret_cast<ushort4*>(z2 + (size_t)row * DIM + tx * 4) = pk.u;
        }
    }
    #pragma unroll
    for (int off = 32; off > 0; off >>= 1)
        amax = fmaxf(amax, __shfl_down(amax, off));
    if ((t & 63) == 0) atomicMax(zmax, __float_as_int(amax));
}

// ---------------- per-node softmax-aggregate (offset trick, no online rescale) --
// wave per node; lane = channels (2*lane, 2*lane+1). zs gathered from fp16 z2;
// zd from fp32 z. m_c = |zd_c| * max|z| bounds e = zs*zd -> exp never overflows.
// hout aliases z: each wave reads only ITS OWN z row, then overwrites it.
__global__ __launch_bounds__(256) void node_kernel(const float* __restrict__ z,
                                                   const unsigned short* __restrict__ z2,
                                                   const int* __restrict__ offsets,
                                                   const int* __restrict__ edge_src,
                                                   const float* __restrict__ snorm,
                                                   const int* __restrict__ zmax,
                                                   float* __restrict__ hout) {
    int tid = threadIdx.x;
    int lane = tid & 63;
    int node = blockIdx.x * 4 + (tid >> 6);   // grid = 7500 exact
    float Mg = __int_as_float(zmax[0]);
    const float2* zp = reinterpret_cast<const float2*>(z);
    float2 zd = zp[(size_t)node * 64 + lane];
    float m0 = fabsf(zd.x) * Mg, m1 = fabsf(zd.y) * Mg;
    int start = offsets[node], end = offsets[node + 1];
    float s0 = 0.f, s1 = 0.f, w0 = 0.f, w1 = 0.f;
    for (int base = start; base < end; base += 64) {
        int cnt = min(64, end - base);
        int es = (base + lane < end) ? edge_src[base + lane] : 0;
        for (int j = 0; j < cnt; ++j) {
            int sn = __builtin_amdgcn_readlane(es, j);
            unsigned v = *reinterpret_cast<const unsigned*>(z2 + (size_t)sn * DIM + lane * 2);
            union { unsigned u; _Float16 f[2]; } cv; cv.u = v;
            float zs0 = (float)cv.f[0], zs1 = (float)cv.f[1];
            float p0 = __expf(fmaf(zs0, zd.x, -m0));
            float p1 = __expf(fmaf(zs1, zd.y, -m1));
            s0 += p0; w0 = fmaf(p0, zs0, w0);
            s1 += p1; w1 = fmaf(p1, zs1, w1);
        }
    }
    float snv = snorm[node];
    float2 o;
    o.x = (s0 > 0.f) ? (w0 / s0) * snv : 0.f;
    o.y = (s1 > 0.f) ? (w1 / s1) * snv : 0.f;
    reinterpret_cast<float2*>(hout)[(size_t)node * 64 + lane] = o;
}

// ---------------- batch-norm statistics ----------------
__global__ __launch_bounds__(256) void reduce_kernel(const float* __restrict__ hout,
                                                     float* __restrict__ redbuf) {
    __shared__ float lsum[256], lsq[256];
    int tid = threadIdx.x;
    int c = tid & 127;
    int half = tid >> 7;
    int rbeg = blockIdx.x * 150;              // grid = 200 exact
    float s = 0.f, q = 0.f;
    for (int r = rbeg + half; r < rbeg + 150; r += 2) {
        float v = hout[(size_t)r * DIM + c];
        s += v; q += v * v;
    }
    lsum[tid] = s; lsq[tid] = q;
    __syncthreads();
    if (tid < 128) {
        s = lsum[tid] + lsum[tid + 128];
        q = lsq[tid] + lsq[tid + 128];
        atomicAdd(&redbuf[c], s);
        atomicAdd(&redbuf[DIM + c], q);
    }
}

__global__ void finalize_kernel(const float* __restrict__ redbuf,
                                const float* __restrict__ gamma,
                                const float* __restrict__ beta,
                                float* __restrict__ params) {
    int c = threadIdx.x;   // 128 threads
    float mu = redbuf[c] * (1.0f / N_NODES);
    float var = redbuf[DIM + c] * (1.0f / N_NODES) - mu * mu;
    float scale = gamma[c] * rsqrtf(var + EPSV);
    params[c] = scale;
    params[DIM + c] = beta[c] - mu * scale;
}

// ---------------- fused BN + ELU + fp32 store ----------------
__global__ __launch_bounds__(256) void elu_kernel(const float* __restrict__ hout,
                                                  const float* __restrict__ params,
                                                  float* __restrict__ out) {
    int idx = (blockIdx.x * 256 + threadIdx.x) * 4;   // grid = 3750 exact
    int c = idx & 127;
    float4 v = reinterpret_cast<const float4*>(hout)[idx >> 2];
    float4 o;
    {
        float y = v.x * params[c + 0] + params[DIM + c + 0];
        o.x = (y > 0.f) ? y : expm1f(y);
        y = v.y * params[c + 1] + params[DIM + c + 1];
        o.y = (y > 0.f) ? y : expm1f(y);
        y = v.z * params[c + 2] + params[DIM + c + 2];
        o.z = (y > 0.f) ? y : expm1f(y);
        y = v.w * params[c + 3] + params[DIM + c + 3];
        o.w = (y > 0.f) ? y : expm1f(y);
    }
    reinterpret_cast<float4*>(out)[idx >> 2] = o;
}

extern "C" void kernel_launch(void* const* d_in, const int* in_sizes, int n_in,
                              void* d_out, int out_size, void* d_ws, size_t ws_size,
                              hipStream_t stream) {
    const float* h     = (const float*)d_in[0];
    const float* snorm = (const float*)d_in[1];
    const float* W     = (const float*)d_in[2];
    const float* gamma = (const float*)d_in[3];
    const float* beta  = (const float*)d_in[4];
    const int*   src   = (const int*)d_in[5];
    const int*   dst   = (const int*)d_in[6];
    float*       out   = (float*)d_out;

    char* ws = (char*)d_ws;
    float*          zbuf     = (float*)         (ws + 0);          // z, later hout (15,360,000 B)
    unsigned short* z2       = (unsigned short*)(ws + 15360000);   //  7,680,000 B (fp16 z)
    int*            counts   = (int*)           (ws + 23040000);   //    120,000 B
    int*            offsets  = (int*)           (ws + 23160000);   //    120,004 B
    int*            cursor   = (int*)           (ws + 23280016);   //    120,000 B
    int*            edge_src = (int*)           (ws + 23400016);   //  1,920,000 B
    float*          redbuf   = (float*)         (ws + 25320016);   //      1,024 B
    float*          params   = (float*)         (ws + 25321040);   //      1,024 B
    int*            zmax     = (int*)           (ws + 25322064);   //          4 B

    zero_kernel<<<118, 256, 0, stream>>>(counts, redbuf, zmax);
    count_kernel<<<(N_EDGES + 255) / 256, 256, 0, stream>>>(dst, counts);
    scan_kernel<<<1, 1024, 0, stream>>>(counts, offsets, cursor);
    fill_kernel<<<(N_EDGES + 255) / 256, 256, 0, stream>>>(src, dst, cursor, edge_src);
    gemm_kernel<<<(N_NODES + 63) / 64, 256, 0, stream>>>(h, W, zbuf, z2, zmax);
    node_kernel<<<N_NODES / 4, 256, 0, stream>>>(zbuf, z2, offsets, edge_src, snorm, zmax, zbuf);
    reduce_kernel<<<200, 256, 0, stream>>>(zbuf, redbuf);
    finalize_kernel<<<1, 128, 0, stream>>>(redbuf, gamma, beta, params);
    elu_kernel<<<(N_NODES * DIM) / 1024, 256, 0, stream>>>(zbuf, params, out);
}